// Round 1
// baseline (321.837 us; speedup 1.0000x reference)
//
#include <hip/hip_runtime.h>

typedef short v8s __attribute__((ext_vector_type(8)));
typedef float v4f __attribute__((ext_vector_type(4)));

#define BM 128
#define BN 128
#define BK 32

__device__ __forceinline__ unsigned short f2bf(float f) {
    unsigned u = __float_as_uint(f);
    unsigned r = u + 0x7fffu + ((u >> 16) & 1u);   // round-to-nearest-even
    return (unsigned short)(r >> 16);
}

__device__ __forceinline__ float bf2f(unsigned short h) {
    return __uint_as_float(((unsigned)h) << 16);
}

__device__ __forceinline__ void async16(const unsigned short* g, unsigned short* l) {
    __builtin_amdgcn_global_load_lds(
        (const __attribute__((address_space(1))) unsigned int*)g,
        (__attribute__((address_space(3))) unsigned int*)l,
        16, 0, 0);
}

// ---------------------------------------------------------------- cast F -> bf16
__global__ void cast_f32_bf16(const float* __restrict__ in,
                              unsigned short* __restrict__ out, int n4) {
    int i = blockIdx.x * blockDim.x + threadIdx.x;
    if (i < n4) {
        float4 v = ((const float4*)in)[i];
        ushort4 o;
        o.x = f2bf(v.x); o.y = f2bf(v.y); o.z = f2bf(v.z); o.w = f2bf(v.w);
        ((ushort4*)out)[i] = o;
    }
}

// ------------------------------------------------- transpose + cast P -> Pt bf16
// P [n x n] fp32 row-major -> Pt [n x n] bf16 with Pt[c][r] = P[r][c]
__global__ void transpose_cast(const float* __restrict__ P,
                               unsigned short* __restrict__ Pt, int n) {
    __shared__ unsigned short tile[32][33];
    int bx = blockIdx.x, by = blockIdx.y;
    int tx = threadIdx.x, ty = threadIdx.y;        // 32 x 8
#pragma unroll
    for (int i = 0; i < 4; i++) {
        int k = bx * 32 + ty + i * 8;
        tile[ty + i * 8][tx] = f2bf(P[(size_t)k * n + by * 32 + tx]);
    }
    __syncthreads();
#pragma unroll
    for (int i = 0; i < 4; i++) {
        int nn = by * 32 + ty + i * 8;
        Pt[(size_t)nn * n + bx * 32 + tx] = tile[tx][ty + i * 8];
    }
}

// --------------------------------------------------------------- GEMM C = A * Bt^T
// A  [M x K] bf16 row-major, Bt [N x K] bf16 row-major.
// MODE 0: write C as bf16 to Zb [M x N].
// MODE 1: adjacency epilogue: a = (r==c) ? 1 : exp(-sqrt(max(sqn[r]+sqn[c]-2*C,0)))
//         written fp32 to Aout [M x N].
template <int MODE>
__global__ void gemm_bt(const unsigned short* __restrict__ A,
                        const unsigned short* __restrict__ Bt,
                        int M, int N, int K,
                        unsigned short* __restrict__ Zb,
                        const float* __restrict__ sqn,
                        float* __restrict__ Aout) {
    __shared__ __align__(16) unsigned short As[BM * BK];
    __shared__ __align__(16) unsigned short Bs[BN * BK];

    const int tid  = threadIdx.x;
    const int lane = tid & 63;
    const int w    = tid >> 6;        // wave 0..3
    const int wr   = w >> 1;          // wave row 0..1
    const int wc   = w & 1;           // wave col 0..1
    const int quad = lane >> 4;
    const int l15  = lane & 15;

    const long rowA0 = (long)blockIdx.y * BM;
    const long rowB0 = (long)blockIdx.x * BN;

    // staging pattern: chunk c covers tile rows [c*16, c*16+16), 1 KiB per chunk
    const int srow = lane >> 2;        // 0..15
    const int scol = (lane & 3) * 8;   // k offset in elements
    const int c0 = w, c1 = w + 4;

    v4f acc[4][4] = {};

    for (int k0 = 0; k0 < K; k0 += BK) {
        __syncthreads();
        async16(A  + (rowA0 + c0 * 16 + srow) * K + k0 + scol, &As[c0 * 512]);
        async16(A  + (rowA0 + c1 * 16 + srow) * K + k0 + scol, &As[c1 * 512]);
        async16(Bt + (rowB0 + c0 * 16 + srow) * K + k0 + scol, &Bs[c0 * 512]);
        async16(Bt + (rowB0 + c1 * 16 + srow) * K + k0 + scol, &Bs[c1 * 512]);
        __syncthreads();

        v8s a[4], b[4];
#pragma unroll
        for (int f = 0; f < 4; ++f)
            a[f] = *(const v8s*)&As[(wr * 64 + f * 16 + l15) * BK + quad * 8];
#pragma unroll
        for (int f = 0; f < 4; ++f)
            b[f] = *(const v8s*)&Bs[(wc * 64 + f * 16 + l15) * BK + quad * 8];
#pragma unroll
        for (int i = 0; i < 4; ++i)
#pragma unroll
            for (int j = 0; j < 4; ++j)
                acc[i][j] = __builtin_amdgcn_mfma_f32_16x16x32_bf16(a[i], b[j], acc[i][j], 0, 0, 0);
    }

    // epilogue
#pragma unroll
    for (int i = 0; i < 4; ++i) {
        int row0 = (int)rowA0 + wr * 64 + i * 16 + quad * 4;
#pragma unroll
        for (int j = 0; j < 4; ++j) {
            int col = (int)rowB0 + wc * 64 + j * 16 + l15;
            if (MODE == 0) {
#pragma unroll
                for (int r = 0; r < 4; ++r)
                    Zb[(long)(row0 + r) * N + col] = f2bf(acc[i][j][r]);
            } else {
                float sc = sqn[col];
#pragma unroll
                for (int r = 0; r < 4; ++r) {
                    int row = row0 + r;
                    float v;
                    if (row == col) {
                        v = 1.0f;
                    } else {
                        float sq = sqn[row] + sc - 2.0f * acc[i][j][r];
                        v = expf(-sqrtf(fmaxf(sq, 0.0f)));
                    }
                    Aout[(long)row * N + col] = v;
                }
            }
        }
    }
}

// ---------------------------------------------------------- row squared norms of Zb
__global__ void row_sqnorm(const unsigned short* __restrict__ Zb,
                           float* __restrict__ sqn, int Kc) {
    int row = blockIdx.x;
    int tid = threadIdx.x;
    const v8s* zr = (const v8s*)(Zb + (size_t)row * Kc);
    float s = 0.0f;
    for (int j = tid; j < Kc / 8; j += 256) {
        v8s v = zr[j];
#pragma unroll
        for (int t = 0; t < 8; ++t) {
            float f = bf2f((unsigned short)v[t]);
            s += f * f;
        }
    }
    for (int off = 32; off > 0; off >>= 1) s += __shfl_down(s, off, 64);
    __shared__ float wsum[4];
    if ((tid & 63) == 0) wsum[tid >> 6] = s;
    __syncthreads();
    if (tid == 0) sqn[row] = wsum[0] + wsum[1] + wsum[2] + wsum[3];
}

// -------------------------------------------------- row sums of A -> dinv = rsqrt
__global__ void rowsum_dinv(const float* __restrict__ Amat,
                            float* __restrict__ dinv, int Nc) {
    int row = blockIdx.x;
    int tid = threadIdx.x;
    const float4* ar = (const float4*)(Amat + (size_t)row * Nc);
    float s = 0.0f;
    for (int j = tid; j < Nc / 4; j += 256) {
        float4 v = ar[j];
        s += v.x + v.y + v.z + v.w;
    }
    for (int off = 32; off > 0; off >>= 1) s += __shfl_down(s, off, 64);
    __shared__ float wsum[4];
    if ((tid & 63) == 0) wsum[tid >> 6] = s;
    __syncthreads();
    if (tid == 0) dinv[row] = rsqrtf(wsum[0] + wsum[1] + wsum[2] + wsum[3]);
}

// -------------------------------------------- normalized = dinv_i * A_ij * dinv_j
__global__ void normalize_k(const float* __restrict__ Amat,
                            const float* __restrict__ dinv,
                            float* __restrict__ outN, int Nc) {
    size_t i4 = (size_t)blockIdx.x * blockDim.x + threadIdx.x;
    size_t idx = i4 * 4;
    int row = (int)(idx / Nc);
    int col = (int)(idx % Nc);
    float di = dinv[row];
    float4 a = ((const float4*)Amat)[i4];
    float4 dj = ((const float4*)dinv)[col / 4];
    float4 o;
    o.x = di * a.x * dj.x;
    o.y = di * a.y * dj.y;
    o.z = di * a.z * dj.z;
    o.w = di * a.w * dj.w;
    ((float4*)outN)[i4] = o;
}

extern "C" void kernel_launch(void* const* d_in, const int* in_sizes, int n_in,
                              void* d_out, int out_size, void* d_ws, size_t ws_size,
                              hipStream_t stream) {
    const int BS_ = 4096, D_ = 2048, R_ = 2048;
    const float* F = (const float*)d_in[0];
    const float* P = (const float*)d_in[1];

    float* outN = (float*)d_out;                      // normalized  [BS x BS]
    float* outA = outN + (size_t)BS_ * BS_;           // adjacency   [BS x BS]

    char* ws = (char*)d_ws;
    unsigned short* Fb  = (unsigned short*)ws;                                   // 16 MB
    unsigned short* Ptb = (unsigned short*)(ws + (size_t)BS_ * D_ * 2);          //  8 MB
    unsigned short* Zb  = (unsigned short*)(ws + (size_t)BS_ * D_ * 2
                                               + (size_t)D_ * R_ * 2);           // 16 MB
    float* sqn  = (float*)(ws + (size_t)BS_ * D_ * 2 + (size_t)D_ * R_ * 2
                              + (size_t)BS_ * R_ * 2);
    float* dinv = sqn + BS_;

    // 1. casts
    cast_f32_bf16<<<(BS_ * D_ / 4 + 255) / 256, 256, 0, stream>>>(F, Fb, BS_ * D_ / 4);
    transpose_cast<<<dim3(D_ / 32, R_ / 32), dim3(32, 8), 0, stream>>>(P, Ptb, D_);

    // 2. Z = F * P   (bf16 out)
    gemm_bt<0><<<dim3(R_ / 128, BS_ / 128), 256, 0, stream>>>(
        Fb, Ptb, BS_, R_, D_, Zb, nullptr, nullptr);

    // 3. row squared norms
    row_sqnorm<<<BS_, 256, 0, stream>>>(Zb, sqn, R_);

    // 4. G = Z * Z^T with fused adjacency epilogue -> outA
    gemm_bt<1><<<dim3(BS_ / 128, BS_ / 128), 256, 0, stream>>>(
        Zb, Zb, BS_, BS_, R_, nullptr, sqn, outA);

    // 5. degree + rsqrt
    rowsum_dinv<<<BS_, 256, 0, stream>>>(outA, dinv, BS_);

    // 6. normalized output
    normalize_k<<<(BS_ * (size_t)BS_ / 4 + 255) / 256, 256, 0, stream>>>(
        outA, dinv, outN, BS_);
}

// Round 2
// 286.570 us; speedup vs baseline: 1.1231x; 1.1231x over previous
//
#include <hip/hip_runtime.h>

typedef short v8s __attribute__((ext_vector_type(8)));
typedef float v4f __attribute__((ext_vector_type(4)));

#define BM 128
#define BN 128
#define BK 32

__device__ __forceinline__ unsigned short f2bf(float f) {
    unsigned u = __float_as_uint(f);
    unsigned r = u + 0x7fffu + ((u >> 16) & 1u);   // round-to-nearest-even
    return (unsigned short)(r >> 16);
}

__device__ __forceinline__ float bf2f(unsigned short h) {
    return __uint_as_float(((unsigned)h) << 16);
}

__device__ __forceinline__ void async16(const unsigned short* g, unsigned short* l) {
    __builtin_amdgcn_global_load_lds(
        (const __attribute__((address_space(1))) unsigned int*)g,
        (__attribute__((address_space(3))) unsigned int*)l,
        16, 0, 0);
}

// ---------------------------------------------------------------- zero scratch
__global__ void zero_k(float* __restrict__ p, int n) {
    int i = blockIdx.x * blockDim.x + threadIdx.x;
    if (i < n) p[i] = 0.0f;
}

// ---------------------------------------------------------------- cast F -> bf16
__global__ void cast_f32_bf16(const float* __restrict__ in,
                              unsigned short* __restrict__ out, int n4) {
    int i = blockIdx.x * blockDim.x + threadIdx.x;
    if (i < n4) {
        float4 v = ((const float4*)in)[i];
        ushort4 o;
        o.x = f2bf(v.x); o.y = f2bf(v.y); o.z = f2bf(v.z); o.w = f2bf(v.w);
        ((ushort4*)out)[i] = o;
    }
}

// ------------------------------------------------- transpose + cast P -> Pt bf16
__global__ void transpose_cast(const float* __restrict__ P,
                               unsigned short* __restrict__ Pt, int n) {
    __shared__ unsigned short tile[32][33];
    int bx = blockIdx.x, by = blockIdx.y;
    int tx = threadIdx.x, ty = threadIdx.y;        // 32 x 8
#pragma unroll
    for (int i = 0; i < 4; i++) {
        int k = bx * 32 + ty + i * 8;
        tile[ty + i * 8][tx] = f2bf(P[(size_t)k * n + by * 32 + tx]);
    }
    __syncthreads();
#pragma unroll
    for (int i = 0; i < 4; i++) {
        int nn = by * 32 + ty + i * 8;
        Pt[(size_t)nn * n + bx * 32 + tx] = tile[tx][ty + i * 8];
    }
}

// ----------------------------------------------------------------- GEMM1: Z = A*Bt^T
// A [M x K], Bt [N x K] bf16 row-major. Writes Zb bf16 and fused row sq-norms
// (of the bf16-rounded Z) via atomicAdd into sqn (must be zeroed first).
__global__ void gemm1(const unsigned short* __restrict__ A,
                      const unsigned short* __restrict__ Bt,
                      int M, int N, int K,
                      unsigned short* __restrict__ Zb,
                      float* __restrict__ sqn) {
    __shared__ __align__(16) unsigned short As[BM * BK];
    __shared__ __align__(16) unsigned short Bs[BN * BK];

    const int tid  = threadIdx.x;
    const int lane = tid & 63;
    const int w    = tid >> 6;
    const int wr   = w >> 1;
    const int wc   = w & 1;
    const int quad = lane >> 4;
    const int l15  = lane & 15;

    const long rowA0 = (long)blockIdx.y * BM;
    const long rowB0 = (long)blockIdx.x * BN;

    // staging: chunk c = 16 rows x 32 cols; XOR-swizzled 16B slot to kill
    // read-side LDS bank conflicts (global_load_lds dest can't be padded).
    const int srow  = lane >> 2;
    const int slotg = (lane & 3) ^ ((srow >> 1) & 3);
    const int scol  = slotg * 8;
    const int c0 = w, c1 = w + 4;
    const int ksw = (l15 >> 1) & 3;   // read-side XOR key (row bits 1..2)

    v4f acc[4][4] = {};

    for (int k0 = 0; k0 < K; k0 += BK) {
        __syncthreads();
        async16(A  + (rowA0 + c0 * 16 + srow) * K + k0 + scol, &As[c0 * 512]);
        async16(A  + (rowA0 + c1 * 16 + srow) * K + k0 + scol, &As[c1 * 512]);
        async16(Bt + (rowB0 + c0 * 16 + srow) * K + k0 + scol, &Bs[c0 * 512]);
        async16(Bt + (rowB0 + c1 * 16 + srow) * K + k0 + scol, &Bs[c1 * 512]);
        __syncthreads();

        v8s a[4], b[4];
#pragma unroll
        for (int f = 0; f < 4; ++f)
            a[f] = *(const v8s*)&As[(wr * 64 + f * 16 + l15) * BK + (quad ^ ksw) * 8];
#pragma unroll
        for (int f = 0; f < 4; ++f)
            b[f] = *(const v8s*)&Bs[(wc * 64 + f * 16 + l15) * BK + (quad ^ ksw) * 8];
#pragma unroll
        for (int i = 0; i < 4; ++i)
#pragma unroll
            for (int j = 0; j < 4; ++j)
                acc[i][j] = __builtin_amdgcn_mfma_f32_16x16x32_bf16(a[i], b[j], acc[i][j], 0, 0, 0);
    }

#pragma unroll
    for (int i = 0; i < 4; ++i) {
        int row0 = (int)rowA0 + wr * 64 + i * 16 + quad * 4;
        float rs[4] = {0.f, 0.f, 0.f, 0.f};
#pragma unroll
        for (int j = 0; j < 4; ++j) {
            int col = (int)rowB0 + wc * 64 + j * 16 + l15;
#pragma unroll
            for (int r = 0; r < 4; ++r) {
                unsigned short b = f2bf(acc[i][j][r]);
                float vb = bf2f(b);
                Zb[(long)(row0 + r) * N + col] = b;
                rs[r] += vb * vb;
            }
        }
#pragma unroll
        for (int r = 0; r < 4; ++r) {
            float s = rs[r];
            s += __shfl_xor(s, 1, 64);
            s += __shfl_xor(s, 2, 64);
            s += __shfl_xor(s, 4, 64);
            s += __shfl_xor(s, 8, 64);
            if (l15 == 0) atomicAdd(&sqn[row0 + r], s);
        }
    }
}

// ------------------------------------------ GEMM2 (symmetric): A = adj(Z*Z^T)
// Upper-triangle 128x128 blocks only; writes tile + transposed tile, fuses
// degree row-sums via atomicAdd into deg (zeroed first).
__global__ void gemm2_sym(const unsigned short* __restrict__ Z,
                          int N, int K,
                          const float* __restrict__ sqn,
                          float* __restrict__ Aout,
                          float* __restrict__ deg) {
    __shared__ __align__(16) unsigned short As[BM * BK];
    __shared__ __align__(16) unsigned short Bs[BN * BK];

    // linear block -> upper-triangle (bi, bj), bi <= bj
    const int nb = N / BN;
    int rem = blockIdx.x, bi = 0;
    while (rem >= nb - bi) { rem -= nb - bi; ++bi; }
    const int bj = bi + rem;
    const bool diag = (bi == bj);

    const int tid  = threadIdx.x;
    const int lane = tid & 63;
    const int w    = tid >> 6;
    const int wr   = w >> 1;
    const int wc   = w & 1;
    const int quad = lane >> 4;
    const int l15  = lane & 15;

    const long rowA0 = (long)bi * BM;
    const long rowB0 = (long)bj * BN;

    const int srow  = lane >> 2;
    const int slotg = (lane & 3) ^ ((srow >> 1) & 3);
    const int scol  = slotg * 8;
    const int c0 = w, c1 = w + 4;
    const int ksw = (l15 >> 1) & 3;

    v4f acc[4][4] = {};

    for (int k0 = 0; k0 < K; k0 += BK) {
        __syncthreads();
        async16(Z + (rowA0 + c0 * 16 + srow) * K + k0 + scol, &As[c0 * 512]);
        async16(Z + (rowA0 + c1 * 16 + srow) * K + k0 + scol, &As[c1 * 512]);
        async16(Z + (rowB0 + c0 * 16 + srow) * K + k0 + scol, &Bs[c0 * 512]);
        async16(Z + (rowB0 + c1 * 16 + srow) * K + k0 + scol, &Bs[c1 * 512]);
        __syncthreads();

        v8s a[4], b[4];
#pragma unroll
        for (int f = 0; f < 4; ++f)
            a[f] = *(const v8s*)&As[(wr * 64 + f * 16 + l15) * BK + (quad ^ ksw) * 8];
#pragma unroll
        for (int f = 0; f < 4; ++f)
            b[f] = *(const v8s*)&Bs[(wc * 64 + f * 16 + l15) * BK + (quad ^ ksw) * 8];
#pragma unroll
        for (int i = 0; i < 4; ++i)
#pragma unroll
            for (int j = 0; j < 4; ++j)
                acc[i][j] = __builtin_amdgcn_mfma_f32_16x16x32_bf16(a[i], b[j], acc[i][j], 0, 0, 0);
    }

    float cs[4] = {0.f, 0.f, 0.f, 0.f};   // column partial sums (per j)
#pragma unroll
    for (int i = 0; i < 4; ++i) {
        int row0 = (int)rowA0 + wr * 64 + i * 16 + quad * 4;
        float rs[4] = {0.f, 0.f, 0.f, 0.f};
#pragma unroll
        for (int j = 0; j < 4; ++j) {
            int col = (int)rowB0 + wc * 64 + j * 16 + l15;
            float sc = sqn[col];
            float vals[4];
#pragma unroll
            for (int r = 0; r < 4; ++r) {
                int row = row0 + r;
                float v;
                if (diag && row == col) {
                    v = 1.0f;
                } else {
                    float sq = sqn[row] + sc - 2.0f * acc[i][j][r];
                    v = __expf(-__fsqrt_rn(fmaxf(sq, 0.0f)));
                }
                vals[r] = v;
                rs[r] += v;
                cs[j] += v;
            }
#pragma unroll
            for (int r = 0; r < 4; ++r)
                Aout[(long)(row0 + r) * N + col] = vals[r];
            if (!diag) {     // transposed tile: 4 consecutive rows -> float4
                float4 t = make_float4(vals[0], vals[1], vals[2], vals[3]);
                *(float4*)&Aout[(long)col * N + row0] = t;
            }
        }
#pragma unroll
        for (int r = 0; r < 4; ++r) {
            float s = rs[r];
            s += __shfl_xor(s, 1, 64);
            s += __shfl_xor(s, 2, 64);
            s += __shfl_xor(s, 4, 64);
            s += __shfl_xor(s, 8, 64);
            if (l15 == 0) atomicAdd(&deg[row0 + r], s);
        }
    }
    if (!diag) {
#pragma unroll
        for (int j = 0; j < 4; ++j) {
            float s = cs[j];
            s += __shfl_xor(s, 16, 64);
            s += __shfl_xor(s, 32, 64);
            if (quad == 0) {
                int col = (int)rowB0 + wc * 64 + j * 16 + l15;
                atomicAdd(&deg[col], s);
            }
        }
    }
}

// ------------------------------------------------------------- dinv = rsqrt(deg)
__global__ void rsqrt_k(const float* __restrict__ deg,
                        float* __restrict__ dinv, int n) {
    int i = blockIdx.x * blockDim.x + threadIdx.x;
    if (i < n) dinv[i] = rsqrtf(deg[i]);
}

// -------------------------------------------- normalized = dinv_i * A_ij * dinv_j
__global__ void normalize_k(const float* __restrict__ Amat,
                            const float* __restrict__ dinv,
                            float* __restrict__ outN, int Nc) {
    size_t i4 = (size_t)blockIdx.x * blockDim.x + threadIdx.x;
    size_t idx = i4 * 4;
    int row = (int)(idx / Nc);
    int col = (int)(idx % Nc);
    float di = dinv[row];
    float4 a = ((const float4*)Amat)[i4];
    float4 dj = ((const float4*)dinv)[col / 4];
    float4 o;
    o.x = di * a.x * dj.x;
    o.y = di * a.y * dj.y;
    o.z = di * a.z * dj.z;
    o.w = di * a.w * dj.w;
    ((float4*)outN)[i4] = o;
}

extern "C" void kernel_launch(void* const* d_in, const int* in_sizes, int n_in,
                              void* d_out, int out_size, void* d_ws, size_t ws_size,
                              hipStream_t stream) {
    const int BS_ = 4096, D_ = 2048, R_ = 2048;
    const float* F = (const float*)d_in[0];
    const float* P = (const float*)d_in[1];

    float* outN = (float*)d_out;                      // normalized  [BS x BS]
    float* outA = outN + (size_t)BS_ * BS_;           // adjacency   [BS x BS]

    char* ws = (char*)d_ws;
    unsigned short* Fb  = (unsigned short*)ws;                                   // 16 MB
    unsigned short* Ptb = (unsigned short*)(ws + (size_t)BS_ * D_ * 2);          //  8 MB
    unsigned short* Zb  = (unsigned short*)(ws + (size_t)BS_ * D_ * 2
                                               + (size_t)D_ * R_ * 2);           // 16 MB
    float* sqn  = (float*)(ws + (size_t)BS_ * D_ * 2 + (size_t)D_ * R_ * 2
                              + (size_t)BS_ * R_ * 2);
    float* deg  = sqn + BS_;
    float* dinv = deg + BS_;

    // 0. zero the atomic accumulators (sqn + deg are adjacent)
    zero_k<<<(2 * BS_ + 255) / 256, 256, 0, stream>>>(sqn, 2 * BS_);

    // 1. casts
    cast_f32_bf16<<<(BS_ * D_ / 4 + 255) / 256, 256, 0, stream>>>(F, Fb, BS_ * D_ / 4);
    transpose_cast<<<dim3(D_ / 32, R_ / 32), dim3(32, 8), 0, stream>>>(P, Ptb, D_);

    // 2. Z = F * P (bf16 out) + fused row sq-norms
    gemm1<<<dim3(R_ / 128, BS_ / 128), 256, 0, stream>>>(
        Fb, Ptb, BS_, R_, D_, Zb, sqn);

    // 3. adjacency from Z*Z^T, upper-triangle blocks, fused degree sums
    const int nb = BS_ / 128;
    gemm2_sym<<<nb * (nb + 1) / 2, 256, 0, stream>>>(Zb, BS_, R_, sqn, outA, deg);

    // 4. dinv = rsqrt(deg)
    rsqrt_k<<<(BS_ + 255) / 256, 256, 0, stream>>>(deg, dinv, BS_);

    // 5. normalized output
    normalize_k<<<(BS_ * (size_t)BS_ / 4 + 255) / 256, 256, 0, stream>>>(
        outA, dinv, outN, BS_);
}